// Round 1
// baseline (653.775 us; speedup 1.0000x reference)
//
#include <hip/hip_runtime.h>

namespace {
constexpr int Bn = 512;
constexpr int Ln = 1024;
constexpr int Vn = 64;
constexpr int En = 128;
constexpr int K  = Vn + En;              // 192
constexpr int WS_FLOATS = En * Vn + En;  // WcT[128][64] + bc[128]
}

// Setup: WcT[j][v] = sum_e W_in[e,v] * W_h[j,e];  bc[j] = b_h[j] + sum_e b_in[e] * W_h[j,e]
__global__ void rnn_setup(const float* __restrict__ W_in, const float* __restrict__ b_in,
                          const float* __restrict__ W_h, const float* __restrict__ b_h,
                          float* __restrict__ ws) {
  const int j = blockIdx.x;   // 0..127
  const int v = threadIdx.x;  // 0..63
  const float* whr = W_h + j * (2 * En);
  float s = 0.f;
#pragma unroll 8
  for (int e = 0; e < En; ++e) s = fmaf(W_in[e * Vn + v], whr[e], s);
  ws[j * Vn + v] = s;
  if (v == 0) {
    float bcv = b_h[j];
    for (int e = 0; e < En; ++e) bcv = fmaf(b_in[e], whr[e], bcv);
    ws[En * Vn + j] = bcv;
  }
}

template <bool USE_WS>
__global__ __launch_bounds__(256) void rnn_main(
    const float* __restrict__ seq, const float* __restrict__ W_in,
    const float* __restrict__ b_in, const float* __restrict__ W_h,
    const float* __restrict__ b_h, const float* __restrict__ W_out,
    const float* __restrict__ b_out, float* __restrict__ out,
    const float* __restrict__ ws) {
  // act[buf][0..63] = seq_t, act[buf][64..191] = h_t
  __shared__ __align__(16) float act[2][K];
  __shared__ __align__(16) float winT[USE_WS ? 4 : En * Vn];     // fallback only: W_in^T [v][e]
  __shared__ __align__(16) float wct_s[USE_WS ? 4 : WS_FLOATS];  // fallback only

  const int tid  = threadIdx.x;
  const int wv   = tid >> 6;        // wave 0..3
  const int l    = tid & 63;        // lane
  const int half = l >> 5;          // K-half: 0 -> e[0..95], 1 -> e[96..191]
  const int j    = wv * 32 + (l & 31);  // output column 0..127
  const int b    = blockIdx.x;

  if constexpr (!USE_WS) {
    // Stage W_in transposed, then compute WcT + bc cooperatively in LDS.
    for (int idx = tid; idx < En * Vn; idx += 256) {
      const int e = idx >> 6, v = idx & 63;  // coalesced read of W_in[e][v]
      winT[v * En + e] = W_in[idx];
    }
    __syncthreads();
    for (int q = 0; q < 32; ++q) {
      const int idx = q * 256 + tid;    // 0..8191
      const int jj = idx & 127;         // per-lane row of W_h
      const int vv = idx >> 7;          // wave-uniform -> LDS broadcast
      const float* whrow = W_h + jj * (2 * En);
      float s = 0.f;
#pragma unroll 8
      for (int e = 0; e < En; ++e) s = fmaf(winT[vv * En + e], whrow[e], s);
      wct_s[jj * Vn + vv] = s;
    }
    if (tid < En) {
      const float* whrow = W_h + tid * (2 * En);
      float s = b_h[tid];
      for (int e = 0; e < En; ++e) s = fmaf(b_in[e], whrow[e], s);
      wct_s[En * Vn + tid] = s;
    }
    __syncthreads();
  }
  const float* wct = USE_WS ? ws : (const float*)wct_s;

  // Per-lane weights: 96 floats = column j, K-half `half` of [Wc ; Whh].
  float4 w[24];
  float bc;
  const float* whr = W_h + j * (2 * En);
  if (half == 0) {
    const float* p = wct + j * Vn;  // WcT[j][0..63] : e 0..63 (seq part)
#pragma unroll
    for (int k2 = 0; k2 < 16; ++k2) w[k2] = ((const float4*)p)[k2];
    const float4* ph = (const float4*)(whr + En);  // Whh rows 0..31 of col j
#pragma unroll
    for (int k2 = 0; k2 < 8; ++k2) w[16 + k2] = ph[k2];
    bc = wct[En * Vn + j];
  } else {
    const float4* ph = (const float4*)(whr + En + 32);  // Whh rows 32..127 of col j
#pragma unroll
    for (int k2 = 0; k2 < 24; ++k2) w[k2] = ph[k2];
    bc = 0.f;
  }

  const float* srow = seq + (size_t)b * (Ln * Vn);

  // init: act[0] = [seq_0, h_0 = 0]
  if (tid < En) act[0][Vn + tid] = 0.f;
  if (tid < 16) *(float4*)&act[0][tid * 4] = *(const float4*)(srow + tid * 4);
  __syncthreads();

  for (int t = 0; t < Ln; ++t) {
    const int cur = t & 1, nxt = cur ^ 1;
    float4 pf;
    const bool do_pf = (tid < 16) && (t + 1 < Ln);
    if (do_pf) pf = *(const float4*)(srow + (t + 1) * Vn + tid * 4);

    const float* a = &act[cur][half * 96];
    float4 acc = {0.f, 0.f, 0.f, 0.f};
#pragma unroll
    for (int kk = 0; kk < 24; ++kk) {
      const float4 av = *(const float4*)(a + 4 * kk);  // wave-broadcast ds_read_b128
      acc.x = fmaf(av.x, w[kk].x, acc.x);
      acc.y = fmaf(av.y, w[kk].y, acc.y);
      acc.z = fmaf(av.z, w[kk].z, acc.z);
      acc.w = fmaf(av.w, w[kk].w, acc.w);
    }
    float s4 = (acc.x + acc.y) + (acc.z + acc.w);
    s4 += __shfl_xor(s4, 32);  // combine the two K-halves (partner lane has same j)
    if (l < 32) act[nxt][Vn + j] = fmaxf(s4 + bc, 0.f);   // h_{t+1}
    if (do_pf) *(float4*)&act[nxt][tid * 4] = pf;         // seq_{t+1}
    __syncthreads();
  }

  // epilogue: out[b][v] = h_final . W_out[v] + b_out[v]
  if (tid < Vn) {
    const float* wo = W_out + tid * En;
    const float* h  = &act[Ln & 1][Vn];
    float o = b_out[tid];
#pragma unroll
    for (int ec = 0; ec < 32; ++ec) {
      const float4 hv  = *(const float4*)(h + 4 * ec);
      const float4 wv4 = *(const float4*)(wo + 4 * ec);
      o = fmaf(hv.x, wv4.x, o);
      o = fmaf(hv.y, wv4.y, o);
      o = fmaf(hv.z, wv4.z, o);
      o = fmaf(hv.w, wv4.w, o);
    }
    out[b * Vn + tid] = o;
  }
}

extern "C" void kernel_launch(void* const* d_in, const int* in_sizes, int n_in,
                              void* d_out, int out_size, void* d_ws, size_t ws_size,
                              hipStream_t stream) {
  const float* seq   = (const float*)d_in[0];
  const float* W_in  = (const float*)d_in[1];
  const float* b_in  = (const float*)d_in[2];
  const float* W_h   = (const float*)d_in[3];
  const float* b_h   = (const float*)d_in[4];
  const float* W_out = (const float*)d_in[5];
  const float* b_out = (const float*)d_in[6];
  float* out = (float*)d_out;
  float* ws  = (float*)d_ws;

  if (ws_size >= (size_t)WS_FLOATS * sizeof(float)) {
    rnn_setup<<<En, Vn, 0, stream>>>(W_in, b_in, W_h, b_h, ws);
    rnn_main<true><<<Bn, 256, 0, stream>>>(seq, W_in, b_in, W_h, b_h, W_out, b_out, out, ws);
  } else {
    rnn_main<false><<<Bn, 256, 0, stream>>>(seq, W_in, b_in, W_h, b_h, W_out, b_out, out, nullptr);
  }
}

// Round 2
// 636.279 us; speedup vs baseline: 1.0275x; 1.0275x over previous
//
#include <hip/hip_runtime.h>

namespace {
constexpr int Bn = 512;
constexpr int Ln = 1024;
constexpr int Vn = 64;
constexpr int En = 128;
constexpr int K  = Vn + En;                    // 192
constexpr int WS_FLOATS = En * K + En;         // Wall[128][192] + bc[128]
}

typedef __attribute__((address_space(1))) const float GF;
typedef __attribute__((address_space(3))) float LF;

// Fold W_in into W_h:  Wall[j][k] : k<64 -> sum_e W_in[e][k]*W_h[j][e] ; k>=64 -> W_h[j][128+(k-64)]
// bc[j] = b_h[j] + sum_e b_in[e]*W_h[j][e]
__global__ void rnn_setup(const float* __restrict__ W_in, const float* __restrict__ b_in,
                          const float* __restrict__ W_h, const float* __restrict__ b_h,
                          float* __restrict__ ws) {
  const int j = blockIdx.x;    // 0..127
  const int k = threadIdx.x;   // 0..191
  const float* whr = W_h + j * (2 * En);
  float s;
  if (k < Vn) {
    s = 0.f;
#pragma unroll 8
    for (int e = 0; e < En; ++e) s = fmaf(W_in[e * Vn + k], whr[e], s);
  } else {
    s = whr[Vn + k];  // W_h[j][128 + (k-64)]
  }
  ws[j * K + k] = s;
  if (k == 0) {
    float b = b_h[j];
    for (int e = 0; e < En; ++e) b = fmaf(b_in[e], whr[e], b);
    ws[En * K + j] = b;
  }
}

__device__ __forceinline__ float quad_reduce(float v) {
  // butterfly within quads of lanes: xor 1 then xor 2 — pure VALU (DPP), no LDS
  int t = __builtin_amdgcn_update_dpp(0, __float_as_int(v), 0xB1, 0xF, 0xF, true); // quad_perm [1,0,3,2]
  v += __int_as_float(t);
  t = __builtin_amdgcn_update_dpp(0, __float_as_int(v), 0x4E, 0xF, 0xF, true);     // quad_perm [2,3,0,1]
  v += __int_as_float(t);
  return v;
}

// fallback weight generation (ws too small): compute Wall[c][kg] on the fly
__device__ __forceinline__ float wall_elem(const float* __restrict__ W_in,
                                           const float* __restrict__ W_h, int c, int kg) {
  const float* whr = W_h + c * (2 * En);
  if (kg >= Vn) return whr[Vn + kg];
  float s = 0.f;
  for (int e = 0; e < En; ++e) s = fmaf(W_in[e * Vn + kg], whr[e], s);
  return s;
}

template <bool USE_WS>
__global__ __launch_bounds__(256, 2) void rnn_main(
    const float* __restrict__ seq, const float* __restrict__ W_in,
    const float* __restrict__ b_in, const float* __restrict__ W_h,
    const float* __restrict__ b_h, const float* __restrict__ W_out,
    const float* __restrict__ b_out, float* __restrict__ out,
    const float* __restrict__ ws) {
  // act[buf][0..63] = seq_t, act[buf][64..191] = h_t   (quad-buffered)
  __shared__ __align__(16) float act[4][K];

  const int tid  = threadIdx.x;
  const int wv   = tid >> 6;                 // wave 0..3
  const int lane = tid & 63;
  const int q    = lane & 3;                 // K-quarter: k in [48q, 48q+48)
  const int p    = wv * 16 + (lane >> 2);    // column pair index 0..63
  const int c0   = 2 * p, c1 = 2 * p + 1;    // owned output columns
  const int b    = blockIdx.x;

  // ---- per-lane weights: 2 cols x 48 k = 24 float4 in VGPRs ----
  float4 w0[12], w1[12];
  float2 bcv;
  if constexpr (USE_WS) {
    const float4* wall4 = (const float4*)ws;
#pragma unroll
    for (int i = 0; i < 12; ++i) {
      w0[i] = wall4[c0 * 48 + 12 * q + i];
      w1[i] = wall4[c1 * 48 + 12 * q + i];
    }
    bcv = *(const float2*)(ws + En * K + c0);
  } else {
#pragma unroll
    for (int i = 0; i < 12; ++i) {
      const int kg = 48 * q + 4 * i;
      w0[i] = make_float4(wall_elem(W_in, W_h, c0, kg),     wall_elem(W_in, W_h, c0, kg + 1),
                          wall_elem(W_in, W_h, c0, kg + 2), wall_elem(W_in, W_h, c0, kg + 3));
      w1[i] = make_float4(wall_elem(W_in, W_h, c1, kg),     wall_elem(W_in, W_h, c1, kg + 1),
                          wall_elem(W_in, W_h, c1, kg + 2), wall_elem(W_in, W_h, c1, kg + 3));
    }
    float bx = b_h[c0], by = b_h[c1];
    for (int e = 0; e < En; ++e) {
      bx = fmaf(b_in[e], W_h[c0 * (2 * En) + e], bx);
      by = fmaf(b_in[e], W_h[c1 * (2 * En) + e], by);
    }
    bcv = make_float2(bx, by);
  }

  const float* srow = seq + (size_t)b * (Ln * Vn);

  // ---- init: seq_0/1/2 -> buf 0/1/2 via global_load_lds (wave 0, 4B/lane = 256B row); h_0 = 0 ----
  if (wv == 0) {
    __builtin_amdgcn_global_load_lds((GF*)(srow + lane),            (LF*)&act[0][0], 4, 0, 0);
    __builtin_amdgcn_global_load_lds((GF*)(srow + Vn + lane),       (LF*)&act[1][0], 4, 0, 0);
    __builtin_amdgcn_global_load_lds((GF*)(srow + 2 * Vn + lane),   (LF*)&act[2][0], 4, 0, 0);
  }
  if (tid < En) act[0][Vn + tid] = 0.f;
  asm volatile("s_waitcnt vmcnt(0) lgkmcnt(0)" ::: "memory");
  __builtin_amdgcn_s_barrier();
  asm volatile("" ::: "memory");

  const float* pf_ptr = srow + 3 * Vn + lane;  // seq_{t+3} source, advanced 64/step

  // Per step: issue prefetch(t+3) -> buf[(t+3)&3]; read buf[t&3]; write h -> buf[(t+1)&3].
  // Raw barrier with vmcnt(2): the two newest prefetches stay in flight across the barrier.
#define RNN_STEP(PH)                                                                     \
  {                                                                                      \
    const int tt = t + (PH);                                                             \
    if (wv == 0 && tt + 3 < Ln)                                                          \
      __builtin_amdgcn_global_load_lds((GF*)pf_ptr, (LF*)&act[((PH) + 3) & 3][0], 4, 0, 0); \
    pf_ptr += Vn;                                                                        \
    const float4* aq = (const float4*)&act[(PH)][48 * q];                                \
    float4 acc0 = {0.f, 0.f, 0.f, 0.f}, acc1 = {0.f, 0.f, 0.f, 0.f};                     \
    _Pragma("unroll")                                                                    \
    for (int i = 0; i < 12; ++i) {                                                       \
      const float4 av = aq[i];                                                           \
      acc0.x = fmaf(av.x, w0[i].x, acc0.x);                                              \
      acc0.y = fmaf(av.y, w0[i].y, acc0.y);                                              \
      acc0.z = fmaf(av.z, w0[i].z, acc0.z);                                              \
      acc0.w = fmaf(av.w, w0[i].w, acc0.w);                                              \
      acc1.x = fmaf(av.x, w1[i].x, acc1.x);                                              \
      acc1.y = fmaf(av.y, w1[i].y, acc1.y);                                              \
      acc1.z = fmaf(av.z, w1[i].z, acc1.z);                                              \
      acc1.w = fmaf(av.w, w1[i].w, acc1.w);                                              \
    }                                                                                    \
    float s0 = (acc0.x + acc0.y) + (acc0.z + acc0.w);                                    \
    float s1 = (acc1.x + acc1.y) + (acc1.z + acc1.w);                                    \
    s0 = quad_reduce(s0);                                                                \
    s1 = quad_reduce(s1);                                                                \
    if (q == 0) {                                                                        \
      float2 hv;                                                                         \
      hv.x = fmaxf(s0 + bcv.x, 0.f);                                                     \
      hv.y = fmaxf(s1 + bcv.y, 0.f);                                                     \
      *(float2*)&act[((PH) + 1) & 3][Vn + c0] = hv;                                      \
    }                                                                                    \
    asm volatile("s_waitcnt vmcnt(2) lgkmcnt(0)" ::: "memory");                          \
    __builtin_amdgcn_s_barrier();                                                        \
    asm volatile("" ::: "memory");                                                       \
  }

#pragma unroll 1
  for (int t = 0; t < Ln; t += 4) {
    RNN_STEP(0)
    RNN_STEP(1)
    RNN_STEP(2)
    RNN_STEP(3)
  }
#undef RNN_STEP

  // ---- epilogue: h_final is in act[0][64..191] (1024 % 4 == 0) ----
  if (tid < Vn) {
    const float* wo = W_out + tid * En;
    const float* h  = &act[0][Vn];
    float o = b_out[tid];
#pragma unroll
    for (int ec = 0; ec < 32; ++ec) {
      const float4 hv  = *(const float4*)(h + 4 * ec);
      const float4 wv4 = *(const float4*)(wo + 4 * ec);
      o = fmaf(hv.x, wv4.x, o);
      o = fmaf(hv.y, wv4.y, o);
      o = fmaf(hv.z, wv4.z, o);
      o = fmaf(hv.w, wv4.w, o);
    }
    out[b * Vn + tid] = o;
  }
}

extern "C" void kernel_launch(void* const* d_in, const int* in_sizes, int n_in,
                              void* d_out, int out_size, void* d_ws, size_t ws_size,
                              hipStream_t stream) {
  const float* seq   = (const float*)d_in[0];
  const float* W_in  = (const float*)d_in[1];
  const float* b_in  = (const float*)d_in[2];
  const float* W_h   = (const float*)d_in[3];
  const float* b_h   = (const float*)d_in[4];
  const float* W_out = (const float*)d_in[5];
  const float* b_out = (const float*)d_in[6];
  float* out = (float*)d_out;
  float* ws  = (float*)d_ws;

  if (ws_size >= (size_t)WS_FLOATS * sizeof(float)) {
    rnn_setup<<<En, K, 0, stream>>>(W_in, b_in, W_h, b_h, ws);
    rnn_main<true><<<Bn, 256, 0, stream>>>(seq, W_in, b_in, W_h, b_h, W_out, b_out, out, ws);
  } else {
    rnn_main<false><<<Bn, 256, 0, stream>>>(seq, W_in, b_in, W_h, b_h, W_out, b_out, out, nullptr);
  }
}